// Round 1
// 261.021 us; speedup vs baseline: 1.0088x; 1.0088x over previous
//
#include <hip/hip_runtime.h>
#include <math.h>

#define U_ 256
#define D_ 5120
#define N_ 16
#define R_ 160
#define J_ 176          // 160 tmp cols + 16 B cols
#define KB 16

typedef float f4v __attribute__((ext_vector_type(4)));

__device__ __forceinline__ float softplus_f(float v) {
    return v > 20.f ? v : log1pf(__expf(v));
}

// ===== K1: partial GEMM — P[ks][j][u] += x[u, kslab] @ [W1|BW][kslab, j] =====
// Thread owns 4 CONSECUTIVE users (b128 LDS reads + b128 P stores).
// Split-K NKS_T slabs for occupancy (>=2 blocks/CU at NKS_T=64).
template<int NKS_T>
__global__ __launch_bounds__(256) void proj_partial(
    const float* __restrict__ x, const float* __restrict__ w1,
    const float* __restrict__ bw, float* __restrict__ P)
{
    constexpr int KSLAB_T = D_ / NKS_T;
    constexpr int STG_T   = KSLAB_T / KB;

    const int jt = blockIdx.x;   // 0..10 (10 == B-proj tile)
    const int ks = blockIdx.y;   // 0..NKS_T-1
    const int t  = threadIdx.x;
    const int uq = t & 63;       // user quad: users uq*4..uq*4+3
    const int jq = t >> 6;       // wave id; j cols jq*4..+3

    __shared__ float xs[KB][260];   // [k][u]; 260 keeps b128 row alignment, ~2-way on writes
    __shared__ float wsh[KB][16];

    const float* wptr; int ldw, jbase;
    if (jt < 10) { wptr = w1; ldw = R_; jbase = jt * 16; }
    else         { wptr = bw; ldw = N_; jbase = 0; }

    const int k0base = ks * KSLAB_T;
    const int ux = t >> 2;
    const int cx = t & 3;

    float acc[4][4] = {};

    float4 xr[4]; float4 wr = make_float4(0.f, 0.f, 0.f, 0.f);

    auto ld = [&](int s_, float4 (&xr_)[4], float4& wr_) {
        const int k0 = k0base + s_ * KB;
#pragma unroll
        for (int i = 0; i < 4; ++i)
            xr_[i] = *(const float4*)&x[(ux + i * 64) * D_ + k0 + cx * 4];
        if (t < 64) {
            const int k = t >> 2, c = t & 3;
            wr_ = *(const float4*)&wptr[(k0 + k) * ldw + jbase + c * 4];
        }
    };

    ld(0, xr, wr);

    for (int s = 0; s < STG_T; ++s) {
#pragma unroll
        for (int i = 0; i < 4; ++i) {
            const int u = ux + i * 64;
            xs[cx * 4 + 0][u] = xr[i].x;
            xs[cx * 4 + 1][u] = xr[i].y;
            xs[cx * 4 + 2][u] = xr[i].z;
            xs[cx * 4 + 3][u] = xr[i].w;
        }
        if (t < 64) *(float4*)&wsh[t >> 2][(t & 3) * 4] = wr;
        __syncthreads();

        float4 xr2[4]; float4 wr2 = make_float4(0.f, 0.f, 0.f, 0.f);
        if (s + 1 < STG_T) ld(s + 1, xr2, wr2);

#pragma unroll
        for (int kk = 0; kk < KB; ++kk) {
            const float4 wv = *(const float4*)&wsh[kk][jq * 4];   // wave-broadcast
            const float4 av = *(const float4*)&xs[kk][uq * 4];    // contiguous b128, conflict-free
            const float avx[4] = {av.x, av.y, av.z, av.w};
            const float wvx[4] = {wv.x, wv.y, wv.z, wv.w};
#pragma unroll
            for (int i = 0; i < 4; ++i)
#pragma unroll
                for (int j = 0; j < 4; ++j)
                    acc[i][j] = fmaf(avx[i], wvx[j], acc[i][j]);
        }
        __syncthreads();
        if (s + 1 < STG_T) {
#pragma unroll
            for (int i = 0; i < 4; ++i) xr[i] = xr2[i];
            wr = wr2;
        }
    }

    // coalesced float4 partial write: P[(ks*J_ + jglob)*256 + uq*4..+3]
#pragma unroll
    for (int j = 0; j < 4; ++j) {
        float* row = P + ((size_t)ks * J_ + jt * 16 + jq * 4 + j) * 256;
        float4 v;
        v.x = acc[0][j]; v.y = acc[1][j]; v.z = acc[2][j]; v.w = acc[3][j];
        *(float4*)&row[uq * 4] = v;
    }
}

// ===== K2: reduce over NKS_T slabs -> tmpT[r][u] (transposed) and Bm[u][n] =====
template<int NKS_T>
__global__ __launch_bounds__(256) void reduce_kernel(
    const float* __restrict__ P, float* __restrict__ tmpT,
    float* __restrict__ Bm)
{
    const int j = blockIdx.x;    // 0..175
    const int u = threadIdx.x;   // 0..255
    float sum = 0.f;
#pragma unroll 8
    for (int ks = 0; ks < NKS_T; ++ks)
        sum += P[((size_t)ks * J_ + j) * 256 + u];
    if (j < R_) tmpT[j * 256 + u] = sum;        // coalesced
    else        Bm[u * N_ + (j - R_)] = sum;    // scattered, 16 KB total
}

// ===== K3: s[u,d] = softplus(tmpT^T @ W2 + bias) * x =====
// 16u x 64d tiles, 64-thread blocks, grid (80,16)=1280 blocks (~5/CU).
__global__ __launch_bounds__(64) void dt_kernel(
    const float* __restrict__ tmpT, const float* __restrict__ w2,
    const float* __restrict__ bias, const float* __restrict__ x,
    float* __restrict__ s)
{
    const int d0 = blockIdx.x * 64;   // 80 tiles
    const int u0 = blockIdx.y * 16;   // 16 tiles
    const int t  = threadIdx.x;       // 0..63
    const int du = t & 3;             // user quad: u0 + du*4..+3
    const int dd = t >> 4 == 0 ? (t >> 2) : (t >> 2);  // d quad 0..15
    const int dq = t >> 2;            // d cols d0 + dq*4..+3

    __shared__ float ts[KB][16];      // tmpT chunk [r][u-in-tile]
    __shared__ float ws_[KB][68];     // w2 chunk [r][d-in-tile], pad keeps 16B align, spreads banks

    float acc[4][4] = {};

    const int rT = t >> 2, cT = t & 3;   // ts staging: 16 rows x 4 f4-cols
    const int rw = t & 15, cw = t >> 4;  // ws_ staging: 16 rows x 4 threads/row

    for (int r0 = 0; r0 < R_; r0 += KB) {
        *(float4*)&ts[rT][cT * 4] =
            *(const float4*)&tmpT[(r0 + rT) * 256 + u0 + cT * 4];
#pragma unroll
        for (int q = 0; q < 4; ++q)
            *(float4*)&ws_[rw][(cw + q * 4) * 4] =
                *(const float4*)&w2[(r0 + rw) * D_ + d0 + (cw + q * 4) * 4];
        __syncthreads();
#pragma unroll
        for (int kk = 0; kk < KB; ++kk) {
            const float4 av = *(const float4*)&ts[kk][du * 4];   // 4-way broadcast b128
            const float4 wv = *(const float4*)&ws_[kk][dq * 4];  // conflict-free b128
            const float avx[4] = {av.x, av.y, av.z, av.w};
            const float wvx[4] = {wv.x, wv.y, wv.z, wv.w};
#pragma unroll
            for (int i = 0; i < 4; ++i)
#pragma unroll
                for (int j = 0; j < 4; ++j)
                    acc[i][j] = fmaf(avx[i], wvx[j], acc[i][j]);
        }
        __syncthreads();
    }

    const int d = d0 + dq * 4;
    const float4 bv = *(const float4*)&bias[d];
#pragma unroll
    for (int i = 0; i < 4; ++i) {
        const int u = u0 + du * 4 + i;
        const float4 xv = *(const float4*)&x[u * D_ + d];
        float4 sv;
        sv.x = softplus_f(acc[i][0] + bv.x) * xv.x;
        sv.y = softplus_f(acc[i][1] + bv.y) * xv.y;
        sv.z = softplus_f(acc[i][2] + bv.z) * xv.z;
        sv.w = softplus_f(acc[i][3] + bv.w) * xv.w;
        *(float4*)&s[u * D_ + d] = sv;
    }
}

// ===== K4: pure stream — out = abar*h + s[u,d]*B[u,n] =====
// All 12 loads issued before first use (deep MLP pipeline), nontemporal
// stores keep `out` from evicting abar/hs from the 256MB L3.
__global__ __launch_bounds__(256) void stream_kernel(
    const float* __restrict__ abar, const float* __restrict__ hs,
    const float* __restrict__ s, const float* __restrict__ Bm,
    float* __restrict__ out)
{
    const int u  = blockIdx.y;                 // 0..255
    const int bx = blockIdx.x;                 // 0..19
    const int t  = threadIdx.x;
    const float4* __restrict__ ab4 = (const float4*)abar;
    const float4* __restrict__ h4  = (const float4*)hs;
    f4v* o4 = (f4v*)out;

    const float* srow = s + u * D_;
    const float4 Bv = ((const float4*)Bm)[u * 4 + (t & 3)];  // n4 = t&3 is k-invariant
    const int base = u * (D_ * 4) + bx * 1024 + t;

    float4 av[4], hv[4];
    float  sv[4];
#pragma unroll
    for (int k = 0; k < 4; ++k) av[k] = ab4[base + k * 256];
#pragma unroll
    for (int k = 0; k < 4; ++k) hv[k] = h4[base + k * 256];
#pragma unroll
    for (int k = 0; k < 4; ++k) sv[k] = srow[(bx * 1024 + k * 256 + t) >> 2];
#pragma unroll
    for (int k = 0; k < 4; ++k) {
        f4v o;
        o.x = fmaf(av[k].x, hv[k].x, sv[k] * Bv.x);
        o.y = fmaf(av[k].y, hv[k].y, sv[k] * Bv.y);
        o.z = fmaf(av[k].z, hv[k].z, sv[k] * Bv.z);
        o.w = fmaf(av[k].w, hv[k].w, sv[k] * Bv.w);
        __builtin_nontemporal_store(o, &o4[base + k * 256]);
    }
}

extern "C" void kernel_launch(void* const* d_in, const int* in_sizes, int n_in,
                              void* d_out, int out_size, void* d_ws, size_t ws_size,
                              hipStream_t stream) {
    const float* x    = (const float*)d_in[0];
    const float* w1   = (const float*)d_in[1];  // [5120,160]
    const float* w2   = (const float*)d_in[2];  // [160,5120]
    const float* bias = (const float*)d_in[3];  // [5120]
    const float* bw   = (const float*)d_in[4];  // [5120,16]
    const float* abar = (const float*)d_in[5];  // [256,5120,16]
    const float* hs   = (const float*)d_in[6];  // [256,5120,16]
    float* out = (float*)d_out;

    float* P = (float*)d_ws;
    const size_t need64 = ((size_t)64 * J_ * 256 + (size_t)R_ * 256 +
                           (size_t)U_ * N_ + (size_t)U_ * D_) * sizeof(float);

    float *tmpT, *Bm, *s;
    if (ws_size >= need64) {
        // NKS=64: P = 11.5 MB, grid 11x64=704 blocks (~2.75/CU)
        tmpT = P + (size_t)64 * J_ * 256;
        Bm   = tmpT + R_ * 256;
        s    = Bm + U_ * N_;
        proj_partial<64><<<dim3(11, 64), 256, 0, stream>>>(x, w1, bw, P);
        reduce_kernel<64><<<dim3(J_), 256, 0, stream>>>(P, tmpT, Bm);
    } else {
        // fallback: previous footprint (9 MB)
        tmpT = P + (size_t)20 * J_ * 256;
        Bm   = tmpT + R_ * 256;
        s    = Bm + U_ * N_;
        proj_partial<20><<<dim3(11, 20), 256, 0, stream>>>(x, w1, bw, P);
        reduce_kernel<20><<<dim3(J_), 256, 0, stream>>>(P, tmpT, Bm);
    }
    dt_kernel<<<dim3(80, 16), 64, 0, stream>>>(tmpT, w2, bias, x, s);
    stream_kernel<<<dim3(20, 256), 256, 0, stream>>>(abar, hs, s, Bm, out);
}